// Round 4
// baseline (6718.375 us; speedup 1.0000x reference)
//
#include <hip/hip_runtime.h>
#include <hip/hip_bf16.h>

#define N_NODES 100000
#define N_EDGES 3200000
#define F_IN    32
#define H       64
#define L_LAYERS 4
#define A_SZ    6158
#define G_SZ    64

#define NBUCK 391           // ceil(N_NODES / 256): bucket = dst >> 8
#define EPB   8192          // edges per block in bucket passes
#define NEBLK 391           // ceil(N_EDGES / EPB)
#define UPD_NODES 128       // nodes per update block

__device__ __forceinline__ float bflo(unsigned u) { return __uint_as_float(u << 16); }
__device__ __forceinline__ float bfhi(unsigned u) { return __uint_as_float(u & 0xffff0000u); }
__device__ __forceinline__ float bfu(unsigned short u) { return __uint_as_float(((unsigned)u) << 16); }
__device__ __forceinline__ unsigned short f2bf(float f) {
    union { __hip_bfloat16 b; unsigned short u; } c;
    c.b = __float2bfloat16(f);
    return c.u;
}

// ---------------------------------------------------------------------------
// CSR build, bucketed (unchanged)
// ---------------------------------------------------------------------------

__global__ __launch_bounds__(256) void bucket_hist_kernel(const int* __restrict__ ei,
                                                          int* __restrict__ bhist) {
    __shared__ int hist[NBUCK];
    int t = threadIdx.x;
    for (int i = t; i < NBUCK; i += 256) hist[i] = 0;
    __syncthreads();
    int base = blockIdx.x * EPB;
    #pragma unroll
    for (int i = 0; i < EPB / 256; ++i) {
        int e = base + i * 256 + t;
        if (e < N_EDGES) atomicAdd(&hist[ei[N_EDGES + e] >> 8], 1);
    }
    __syncthreads();
    for (int i = t; i < NBUCK; i += 256)
        if (hist[i]) atomicAdd(&bhist[i], hist[i]);
}

__global__ void bucket_scan_kernel(const int* __restrict__ bhist,
                                   int* __restrict__ bucket_base,
                                   int* __restrict__ bcursor) {
    __shared__ int s[512];
    int t = threadIdx.x;
    int v = (t < NBUCK) ? bhist[t] : 0;
    s[t] = v;
    __syncthreads();
    for (int off = 1; off < 512; off <<= 1) {
        int x = (t >= off) ? s[t - off] : 0;
        __syncthreads();
        s[t] += x;
        __syncthreads();
    }
    if (t < NBUCK) {
        int excl = s[t] - v;
        bucket_base[t] = excl;
        bcursor[t] = excl;
    }
    if (t == 0) bucket_base[NBUCK] = N_EDGES;
}

__global__ __launch_bounds__(256) void bucket_scatter_kernel(const int* __restrict__ ei,
                                                             int* __restrict__ bcursor,
                                                             unsigned int* __restrict__ pairs) {
    __shared__ int hist[NBUCK];
    __shared__ int cur[NBUCK];
    int t = threadIdx.x;
    for (int i = t; i < NBUCK; i += 256) hist[i] = 0;
    __syncthreads();
    int base = blockIdx.x * EPB;
    #pragma unroll
    for (int i = 0; i < EPB / 256; ++i) {
        int e = base + i * 256 + t;
        if (e < N_EDGES) atomicAdd(&hist[ei[N_EDGES + e] >> 8], 1);
    }
    __syncthreads();
    for (int i = t; i < NBUCK; i += 256) {
        int c = hist[i];
        cur[i] = c ? atomicAdd(&bcursor[i], c) : 0;
    }
    __syncthreads();
    #pragma unroll
    for (int i = 0; i < EPB / 256; ++i) {
        int e = base + i * 256 + t;
        if (e < N_EDGES) {
            int src = ei[e];
            int dst = ei[N_EDGES + e];
            int b = dst >> 8;
            int idx = atomicAdd(&cur[b], 1);
            pairs[idx] = ((unsigned int)(dst & 255) << 17) | (unsigned int)src;
        }
    }
}

__global__ __launch_bounds__(256) void bucket_rank_kernel(const unsigned int* __restrict__ pairs,
                                                          const int* __restrict__ bucket_base,
                                                          int* __restrict__ row_start,
                                                          float* __restrict__ inv_deg,
                                                          int* __restrict__ src_sorted) {
    __shared__ int cnt[256];
    __shared__ int scn[256];
    __shared__ int cur[256];
    int b = blockIdx.x;
    int t = threadIdx.x;
    int nb0 = b << 8;
    int e0 = bucket_base[b];
    int e1 = bucket_base[b + 1];
    cnt[t] = 0;
    __syncthreads();
    for (int e = e0 + t; e < e1; e += 256)
        atomicAdd(&cnt[pairs[e] >> 17], 1);
    __syncthreads();
    int v = cnt[t];
    scn[t] = v;
    __syncthreads();
    for (int off = 1; off < 256; off <<= 1) {
        int x = (t >= off) ? scn[t - off] : 0;
        __syncthreads();
        scn[t] += x;
        __syncthreads();
    }
    int excl = scn[t] - v;
    int n = nb0 + t;
    if (n < N_NODES) {
        row_start[n] = e0 + excl;
        inv_deg[n] = 1.0f / (float)max(v, 1);
    }
    cur[t] = e0 + excl;
    __syncthreads();
    for (int e = e0 + t; e < e1; e += 256) {
        unsigned int p = pairs[e];
        int slot = atomicAdd(&cur[p >> 17], 1);
        src_sorted[slot] = (int)(p & 0x1FFFFu);
    }
    if (b == 0 && t == 0) row_start[N_NODES] = N_EDGES;
}

// ---------------------------------------------------------------------------
// Encoder: h16 = bf16(relu(x @ W_enc.T + b_enc))
// ---------------------------------------------------------------------------

__global__ __launch_bounds__(256) void encoder_kernel(const float* __restrict__ x,
                                                      const float* __restrict__ W_enc,
                                                      const float* __restrict__ b_enc,
                                                      unsigned short* __restrict__ h16) {
    __shared__ float Wt[F_IN][H + 1];
    __shared__ float xl[4][F_IN];
    int t = threadIdx.x;
    #pragma unroll
    for (int r = 0; r < 8; ++r) {
        int idx = r * 256 + t;
        Wt[idx & 31][idx >> 5] = W_enc[idx];
    }
    int nb = blockIdx.x * 4;
    if (t < 128) ((float*)xl)[t] = x[nb * F_IN + t];
    __syncthreads();
    int n = t >> 6;
    int f = t & 63;
    float acc = b_enc[f];
    #pragma unroll
    for (int k = 0; k < F_IN; ++k) acc += xl[n][k] * Wt[k][f];
    h16[(size_t)(nb + n) * H + f] = f2bf(fmaxf(acc, 0.0f));
}

// ---------------------------------------------------------------------------
// Aggregate: mean of h16 rows over incoming neighbors -> bf16 agg16.
// 2 nodes per wave: 32 lanes per node, lane j holds packed features (2j,2j+1).
// ---------------------------------------------------------------------------

__global__ __launch_bounds__(256) void aggregate_kernel(const unsigned short* __restrict__ h16,
                                                        const int* __restrict__ row_start,
                                                        const int* __restrict__ src_sorted,
                                                        const float* __restrict__ inv_deg,
                                                        unsigned int* __restrict__ agg16) {
    int t = threadIdx.x;
    int wave = (blockIdx.x << 2) + (t >> 6);
    int lane = t & 63;
    int half = lane >> 5;
    int j = lane & 31;
    int node = (wave << 1) + half;
    if (node >= N_NODES) return;
    int s = row_start[node];
    int e = row_start[node + 1];
    float a0 = 0.f, a1 = 0.f, b0 = 0.f, b1 = 0.f;
    float c0 = 0.f, c1 = 0.f, d0 = 0.f, d1 = 0.f;
    int i = s;
    for (; i + 3 < e; i += 4) {
        int s0 = src_sorted[i], s1 = src_sorted[i + 1];
        int s2 = src_sorted[i + 2], s3 = src_sorted[i + 3];
        unsigned u0 = *(const unsigned*)(h16 + (size_t)s0 * H + 2 * j);
        unsigned u1 = *(const unsigned*)(h16 + (size_t)s1 * H + 2 * j);
        unsigned u2 = *(const unsigned*)(h16 + (size_t)s2 * H + 2 * j);
        unsigned u3 = *(const unsigned*)(h16 + (size_t)s3 * H + 2 * j);
        a0 += bflo(u0); a1 += bfhi(u0);
        b0 += bflo(u1); b1 += bfhi(u1);
        c0 += bflo(u2); c1 += bfhi(u2);
        d0 += bflo(u3); d1 += bfhi(u3);
    }
    for (; i < e; ++i) {
        unsigned u = *(const unsigned*)(h16 + (size_t)src_sorted[i] * H + 2 * j);
        a0 += bflo(u); a1 += bfhi(u);
    }
    float inv = inv_deg[node];
    float r0 = ((a0 + b0) + (c0 + d0)) * inv;
    float r1 = ((a1 + b1) + (c1 + d1)) * inv;
    agg16[(size_t)node * 32 + j] = (unsigned)f2bf(r0) | ((unsigned)f2bf(r1) << 16);
}

// ---------------------------------------------------------------------------
// SAGE update: h16 = bf16(relu(agg @ Wl.T + bl + h @ Wr.T) + h)
// Register-tiled: 128 nodes/block, lane computes 4 nodes x 8 feats.
// bf16 operands in XOR-swizzled LDS -> conflict-free b64 reads.
// ---------------------------------------------------------------------------

__global__ __launch_bounds__(256) void update_kernel(const float* __restrict__ Wl,
                                                     const float* __restrict__ bl,
                                                     const float* __restrict__ Wr,
                                                     const unsigned short* __restrict__ agg16,
                                                     unsigned short* __restrict__ h16) {
    __shared__ __align__(16) unsigned short Ws[2][64 * 64];        // [mat][f*64+k] swizzled
    __shared__ __align__(16) unsigned short As[2][UPD_NODES * 64]; // [arr][n*64+k] swizzled
    int t = threadIdx.x;
    int nb = blockIdx.x * UPD_NODES;

    // stage weights (fp32 -> bf16), 16 elems per thread
    #pragma unroll
    for (int p = 0; p < 8; ++p) {
        int e = t * 16 + p * 2;
        float2 wl2 = *(const float2*)(Wl + e);
        float2 wr2 = *(const float2*)(Wr + e);
        unsigned pl = (unsigned)f2bf(wl2.x) | ((unsigned)f2bf(wl2.y) << 16);
        unsigned pr = (unsigned)f2bf(wr2.x) | ((unsigned)f2bf(wr2.y) << 16);
        int f = e >> 6, k = e & 63;
        int idx = (f * 64 + k) ^ (((f >> 3) & 7) << 3);
        *(unsigned*)&Ws[0][idx] = pl;
        *(unsigned*)&Ws[1][idx] = pr;
    }
    // stage activations: thread t -> node t>>1, 16B-chunks (t&1)*4..+3
    {
        int node = t >> 1;
        int gi = nb + node;
        if (gi < N_NODES) {
            const uint4* sa = (const uint4*)((const unsigned short*)agg16 + (size_t)gi * 64);
            const uint4* sh = (const uint4*)(h16 + (size_t)gi * 64);
            #pragma unroll
            for (int c0 = 0; c0 < 4; ++c0) {
                int c = (t & 1) * 4 + c0;
                int idx = (node * 64 + c * 8) ^ (((node >> 2) & 7) << 3);
                *(uint4*)&As[0][idx] = sa[c];
                *(uint4*)&As[1][idx] = sh[c];
            }
        }
    }
    __syncthreads();

    int lane = t & 63;
    int w = t >> 6;
    int fg = lane & 7;
    int g = lane >> 3;
    int nloc = w * 32 + g * 4;
    int f0 = fg * 8;

    float bias[8];
    #pragma unroll
    for (int j = 0; j < 8; ++j) bias[j] = bl[f0 + j];

    float acc[4][8];
    #pragma unroll
    for (int i = 0; i < 4; ++i)
        #pragma unroll
        for (int j = 0; j < 8; ++j) acc[i][j] = 0.f;

    #pragma unroll
    for (int kq = 0; kq < 16; ++kq) {
        float wlv[8][4], wrv[8][4];
        #pragma unroll
        for (int j = 0; j < 8; ++j) {
            int f = f0 + j;
            int idx = (f * 64 + kq * 4) ^ (((f >> 3) & 7) << 3);
            uint2 wa = *(const uint2*)&Ws[0][idx];
            uint2 wb = *(const uint2*)&Ws[1][idx];
            wlv[j][0] = bflo(wa.x); wlv[j][1] = bfhi(wa.x);
            wlv[j][2] = bflo(wa.y); wlv[j][3] = bfhi(wa.y);
            wrv[j][0] = bflo(wb.x); wrv[j][1] = bfhi(wb.x);
            wrv[j][2] = bflo(wb.y); wrv[j][3] = bfhi(wb.y);
        }
        #pragma unroll
        for (int i = 0; i < 4; ++i) {
            int n = nloc + i;
            int idx = (n * 64 + kq * 4) ^ (((n >> 2) & 7) << 3);
            uint2 av = *(const uint2*)&As[0][idx];
            uint2 hv = *(const uint2*)&As[1][idx];
            float a0 = bflo(av.x), a1 = bfhi(av.x), a2 = bflo(av.y), a3 = bfhi(av.y);
            float q0 = bflo(hv.x), q1 = bfhi(hv.x), q2 = bflo(hv.y), q3 = bfhi(hv.y);
            #pragma unroll
            for (int j = 0; j < 8; ++j) {
                acc[i][j] += a0 * wlv[j][0] + a1 * wlv[j][1] + a2 * wlv[j][2] + a3 * wlv[j][3]
                           + q0 * wrv[j][0] + q1 * wrv[j][1] + q2 * wrv[j][2] + q3 * wrv[j][3];
            }
        }
    }

    #pragma unroll
    for (int i = 0; i < 4; ++i) {
        int n = nloc + i;
        int gi = nb + n;
        if (gi < N_NODES) {
            int idx = (n * 64 + f0) ^ (((n >> 2) & 7) << 3);
            uint4 hv4 = *(const uint4*)&As[1][idx];
            float hr[8] = { bflo(hv4.x), bfhi(hv4.x), bflo(hv4.y), bfhi(hv4.y),
                            bflo(hv4.z), bfhi(hv4.z), bflo(hv4.w), bfhi(hv4.w) };
            unsigned o[4];
            #pragma unroll
            for (int jj = 0; jj < 4; ++jj) {
                float v0 = fmaxf(acc[i][2 * jj]     + bias[2 * jj],     0.f) + hr[2 * jj];
                float v1 = fmaxf(acc[i][2 * jj + 1] + bias[2 * jj + 1], 0.f) + hr[2 * jj + 1];
                o[jj] = (unsigned)f2bf(v0) | ((unsigned)f2bf(v1) << 16);
            }
            *((uint4*)(h16 + (size_t)gi * 64) + fg) = make_uint4(o[0], o[1], o[2], o[3]);
        }
    }
}

// ---------------------------------------------------------------------------
// Pool: 32 nodes/wave, same-graph fast path (batch sorted)
// ---------------------------------------------------------------------------

__global__ __launch_bounds__(256) void pool_kernel(const unsigned short* __restrict__ h16,
                                                   const int* __restrict__ batch,
                                                   float* __restrict__ gsum,
                                                   float* __restrict__ gcount) {
    int w = blockIdx.x * 4 + (threadIdx.x >> 6);
    int f = threadIdx.x & 63;
    int n0 = w * 32;
    if (n0 >= N_NODES) return;
    int n1 = min(n0 + 32, N_NODES);
    int g0 = batch[n0];
    int gend = batch[n1 - 1];
    if (g0 == gend) {
        float a0 = 0.f, a1 = 0.f, a2 = 0.f, a3 = 0.f;
        int n = n0;
        for (; n + 3 < n1; n += 4) {
            a0 += bfu(h16[(size_t)n * H + f]);
            a1 += bfu(h16[(size_t)(n + 1) * H + f]);
            a2 += bfu(h16[(size_t)(n + 2) * H + f]);
            a3 += bfu(h16[(size_t)(n + 3) * H + f]);
        }
        for (; n < n1; ++n) a0 += bfu(h16[(size_t)n * H + f]);
        atomicAdd(&gsum[g0 * H + f], (a0 + a1) + (a2 + a3));
        if (f == 0) atomicAdd(&gcount[g0], (float)(n1 - n0));
    } else {
        int curg = g0;
        float acc = 0.f;
        int cnt = 0;
        for (int n = n0; n < n1; ++n) {
            int g = batch[n];
            if (g != curg) {
                atomicAdd(&gsum[curg * H + f], acc);
                if (f == 0) atomicAdd(&gcount[curg], (float)cnt);
                acc = 0.f; cnt = 0; curg = g;
            }
            acc += bfu(h16[(size_t)n * H + f]);
            ++cnt;
        }
        atomicAdd(&gsum[curg * H + f], acc);
        if (f == 0) atomicAdd(&gcount[curg], (float)cnt);
    }
}

// ---------------------------------------------------------------------------
// Heads (unchanged)
// ---------------------------------------------------------------------------

__global__ __launch_bounds__(256) void policy_kernel(const float* __restrict__ gsum,
                                                     const float* __restrict__ gcount,
                                                     const float* __restrict__ Wp,
                                                     const float* __restrict__ bp,
                                                     float* __restrict__ out) {
    __shared__ float gr[H];
    int g = blockIdx.y;
    int t = threadIdx.x;
    if (t < H) {
        float inv = 1.0f / fmaxf(gcount[g], 1.0f);
        gr[t] = gsum[g * H + t] * inv;
    }
    __syncthreads();
    int a = blockIdx.x * 256 + t;
    if (a >= A_SZ) return;
    const float4* wp4 = (const float4*)(Wp + a * H);
    float acc = bp[a];
    #pragma unroll
    for (int c = 0; c < 16; ++c) {
        float4 wv = wp4[c];
        acc += gr[4 * c + 0] * wv.x + gr[4 * c + 1] * wv.y
             + gr[4 * c + 2] * wv.z + gr[4 * c + 3] * wv.w;
    }
    out[g * A_SZ + a] = acc;
}

__global__ void value_kernel(const float* __restrict__ gsum, const float* __restrict__ gcount,
                             const float* __restrict__ Wv, const float* __restrict__ bv,
                             float* __restrict__ out) {
    int g = threadIdx.x;
    if (g >= G_SZ) return;
    float inv = 1.0f / fmaxf(gcount[g], 1.0f);
    float acc = bv[0];
    #pragma unroll
    for (int k = 0; k < H; ++k) acc += gsum[g * H + k] * inv * Wv[k];
    out[G_SZ * A_SZ + g] = tanhf(acc);
}

// ---------------------------------------------------------------------------

extern "C" void kernel_launch(void* const* d_in, const int* in_sizes, int n_in,
                              void* d_out, int out_size, void* d_ws, size_t ws_size,
                              hipStream_t stream) {
    const float* x     = (const float*)d_in[0];
    const int*   ei    = (const int*)d_in[1];
    const int*   batch = (const int*)d_in[2];
    const float* W_enc = (const float*)d_in[3];
    const float* b_enc = (const float*)d_in[4];
    const float* Wl    = (const float*)d_in[5];
    const float* bl    = (const float*)d_in[6];
    const float* Wr    = (const float*)d_in[7];
    const float* Wp    = (const float*)d_in[8];
    const float* bp    = (const float*)d_in[9];
    const float* Wv    = (const float*)d_in[10];
    const float* bv    = (const float*)d_in[11];
    float* out = (float*)d_out;

    char* ws = (char*)d_ws;
    size_t off = 0;
    auto alloc = [&](size_t bytes) {
        char* p = ws + off;
        off = (off + bytes + 255) & ~(size_t)255;
        return p;
    };
    unsigned short* h16   = (unsigned short*)alloc((size_t)N_NODES * H * 2);
    unsigned int*   agg16 = (unsigned int*)alloc((size_t)N_NODES * H * 2);
    int* row_start        = (int*)alloc((size_t)(N_NODES + 1) * 4);
    float* inv_deg        = (float*)alloc((size_t)N_NODES * 4);
    int* src_sorted       = (int*)alloc((size_t)N_EDGES * 4);
    unsigned int* pairs   = (unsigned int*)alloc((size_t)N_EDGES * 4);
    int* bhist            = (int*)alloc((NBUCK + 8) * 4);
    int* bucket_base      = (int*)alloc((NBUCK + 8) * 4);
    int* bcursor          = (int*)alloc((NBUCK + 8) * 4);
    float* gsum           = (float*)alloc((size_t)(G_SZ * H + G_SZ) * 4);
    float* gcount         = gsum + G_SZ * H;

    // CSR build (bucketed)
    hipMemsetAsync(bhist, 0, NBUCK * 4, stream);
    bucket_hist_kernel<<<NEBLK, 256, 0, stream>>>(ei, bhist);
    bucket_scan_kernel<<<1, 512, 0, stream>>>(bhist, bucket_base, bcursor);
    bucket_scatter_kernel<<<NEBLK, 256, 0, stream>>>(ei, bcursor, pairs);
    bucket_rank_kernel<<<NBUCK, 256, 0, stream>>>(pairs, bucket_base, row_start,
                                                  inv_deg, src_sorted);

    encoder_kernel<<<N_NODES / 4, 256, 0, stream>>>(x, W_enc, b_enc, h16);

    const int UPD_BLOCKS = (N_NODES + UPD_NODES - 1) / UPD_NODES;  // 782
    for (int l = 0; l < L_LAYERS; ++l) {
        aggregate_kernel<<<N_NODES / 8, 256, 0, stream>>>(h16, row_start, src_sorted,
                                                          inv_deg, agg16);
        update_kernel<<<UPD_BLOCKS, 256, 0, stream>>>(Wl + (size_t)l * H * H, bl + l * H,
                                                      Wr + (size_t)l * H * H,
                                                      (const unsigned short*)agg16, h16);
    }

    hipMemsetAsync(gsum, 0, (size_t)(G_SZ * H + G_SZ) * 4, stream);
    const int POOL_BLOCKS = (N_NODES / 32 + 3) / 4 + 1;  // 782
    pool_kernel<<<POOL_BLOCKS, 256, 0, stream>>>(h16, batch, gsum, gcount);
    policy_kernel<<<dim3((A_SZ + 255) / 256, G_SZ), 256, 0, stream>>>(gsum, gcount, Wp, bp, out);
    value_kernel<<<1, 64, 0, stream>>>(gsum, gcount, Wv, bv, out);
}

// Round 5
// 668.503 us; speedup vs baseline: 10.0499x; 10.0499x over previous
//
#include <hip/hip_runtime.h>
#include <hip/hip_bf16.h>

#define N_NODES 100000
#define N_EDGES 3200000
#define F_IN    32
#define H       64
#define L_LAYERS 4
#define A_SZ    6158
#define G_SZ    64

#define NBUCK 391           // ceil(N_NODES / 256): bucket = dst >> 8
#define EPB   8192          // edges per block in bucket passes
#define NEBLK 391           // ceil(N_EDGES / EPB)

typedef __attribute__((ext_vector_type(8))) short bf16x8;
typedef __attribute__((ext_vector_type(4))) float f32x4;

__device__ __forceinline__ float bflo(unsigned u) { return __uint_as_float(u << 16); }
__device__ __forceinline__ float bfhi(unsigned u) { return __uint_as_float(u & 0xffff0000u); }
__device__ __forceinline__ float bfu(unsigned short u) { return __uint_as_float(((unsigned)u) << 16); }
__device__ __forceinline__ unsigned short f2bf(float f) {
    union { __hip_bfloat16 b; unsigned short u; } c;
    c.b = __float2bfloat16(f);
    return c.u;
}
__device__ __forceinline__ bf16x8 ldfrag(const unsigned short* p) {
    union { uint4 u; bf16x8 v; } c;
    c.u = *(const uint4*)p;
    return c.v;
}
__device__ __forceinline__ bf16x8 cvt8(const float* p) {
    float4 lo = *(const float4*)p;
    float4 hi = *(const float4*)(p + 4);
    bf16x8 r;
    r[0] = (short)f2bf(lo.x); r[1] = (short)f2bf(lo.y);
    r[2] = (short)f2bf(lo.z); r[3] = (short)f2bf(lo.w);
    r[4] = (short)f2bf(hi.x); r[5] = (short)f2bf(hi.y);
    r[6] = (short)f2bf(hi.z); r[7] = (short)f2bf(hi.w);
    return r;
}

// ---------------------------------------------------------------------------
// CSR build, bucketed (unchanged)
// ---------------------------------------------------------------------------

__global__ __launch_bounds__(256) void bucket_hist_kernel(const int* __restrict__ ei,
                                                          int* __restrict__ bhist) {
    __shared__ int hist[NBUCK];
    int t = threadIdx.x;
    for (int i = t; i < NBUCK; i += 256) hist[i] = 0;
    __syncthreads();
    int base = blockIdx.x * EPB;
    #pragma unroll
    for (int i = 0; i < EPB / 256; ++i) {
        int e = base + i * 256 + t;
        if (e < N_EDGES) atomicAdd(&hist[ei[N_EDGES + e] >> 8], 1);
    }
    __syncthreads();
    for (int i = t; i < NBUCK; i += 256)
        if (hist[i]) atomicAdd(&bhist[i], hist[i]);
}

__global__ void bucket_scan_kernel(const int* __restrict__ bhist,
                                   int* __restrict__ bucket_base,
                                   int* __restrict__ bcursor) {
    __shared__ int s[512];
    int t = threadIdx.x;
    int v = (t < NBUCK) ? bhist[t] : 0;
    s[t] = v;
    __syncthreads();
    for (int off = 1; off < 512; off <<= 1) {
        int x = (t >= off) ? s[t - off] : 0;
        __syncthreads();
        s[t] += x;
        __syncthreads();
    }
    if (t < NBUCK) {
        int excl = s[t] - v;
        bucket_base[t] = excl;
        bcursor[t] = excl;
    }
    if (t == 0) bucket_base[NBUCK] = N_EDGES;
}

__global__ __launch_bounds__(256) void bucket_scatter_kernel(const int* __restrict__ ei,
                                                             int* __restrict__ bcursor,
                                                             unsigned int* __restrict__ pairs) {
    __shared__ int hist[NBUCK];
    __shared__ int cur[NBUCK];
    int t = threadIdx.x;
    for (int i = t; i < NBUCK; i += 256) hist[i] = 0;
    __syncthreads();
    int base = blockIdx.x * EPB;
    #pragma unroll
    for (int i = 0; i < EPB / 256; ++i) {
        int e = base + i * 256 + t;
        if (e < N_EDGES) atomicAdd(&hist[ei[N_EDGES + e] >> 8], 1);
    }
    __syncthreads();
    for (int i = t; i < NBUCK; i += 256) {
        int c = hist[i];
        cur[i] = c ? atomicAdd(&bcursor[i], c) : 0;
    }
    __syncthreads();
    #pragma unroll
    for (int i = 0; i < EPB / 256; ++i) {
        int e = base + i * 256 + t;
        if (e < N_EDGES) {
            int src = ei[e];
            int dst = ei[N_EDGES + e];
            int b = dst >> 8;
            int idx = atomicAdd(&cur[b], 1);
            pairs[idx] = ((unsigned int)(dst & 255) << 17) | (unsigned int)src;
        }
    }
}

__global__ __launch_bounds__(256) void bucket_rank_kernel(const unsigned int* __restrict__ pairs,
                                                          const int* __restrict__ bucket_base,
                                                          int* __restrict__ row_start,
                                                          float* __restrict__ inv_deg,
                                                          int* __restrict__ src_sorted) {
    __shared__ int cnt[256];
    __shared__ int scn[256];
    __shared__ int cur[256];
    int b = blockIdx.x;
    int t = threadIdx.x;
    int nb0 = b << 8;
    int e0 = bucket_base[b];
    int e1 = bucket_base[b + 1];
    cnt[t] = 0;
    __syncthreads();
    for (int e = e0 + t; e < e1; e += 256)
        atomicAdd(&cnt[pairs[e] >> 17], 1);
    __syncthreads();
    int v = cnt[t];
    scn[t] = v;
    __syncthreads();
    for (int off = 1; off < 256; off <<= 1) {
        int x = (t >= off) ? scn[t - off] : 0;
        __syncthreads();
        scn[t] += x;
        __syncthreads();
    }
    int excl = scn[t] - v;
    int n = nb0 + t;
    if (n < N_NODES) {
        row_start[n] = e0 + excl;
        inv_deg[n] = 1.0f / (float)max(v, 1);
    }
    cur[t] = e0 + excl;
    __syncthreads();
    for (int e = e0 + t; e < e1; e += 256) {
        unsigned int p = pairs[e];
        int slot = atomicAdd(&cur[p >> 17], 1);
        src_sorted[slot] = (int)(p & 0x1FFFFu);
    }
    if (b == 0 && t == 0) row_start[N_NODES] = N_EDGES;
}

// ---------------------------------------------------------------------------
// Encoder: h16 = bf16(relu(x @ W_enc.T + b_enc))
// ---------------------------------------------------------------------------

__global__ __launch_bounds__(256) void encoder_kernel(const float* __restrict__ x,
                                                      const float* __restrict__ W_enc,
                                                      const float* __restrict__ b_enc,
                                                      unsigned short* __restrict__ h16) {
    __shared__ float Wt[F_IN][H + 1];
    __shared__ float xl[4][F_IN];
    int t = threadIdx.x;
    #pragma unroll
    for (int r = 0; r < 8; ++r) {
        int idx = r * 256 + t;
        Wt[idx & 31][idx >> 5] = W_enc[idx];
    }
    int nb = blockIdx.x * 4;
    if (t < 128) ((float*)xl)[t] = x[nb * F_IN + t];
    __syncthreads();
    int n = t >> 6;
    int f = t & 63;
    float acc = b_enc[f];
    #pragma unroll
    for (int k = 0; k < F_IN; ++k) acc += xl[n][k] * Wt[k][f];
    h16[(size_t)(nb + n) * H + f] = f2bf(fmaxf(acc, 0.0f));
}

// ---------------------------------------------------------------------------
// Aggregate: mean of h16 rows over incoming neighbors -> bf16 agg16.
// ---------------------------------------------------------------------------

__global__ __launch_bounds__(256) void aggregate_kernel(const unsigned short* __restrict__ h16,
                                                        const int* __restrict__ row_start,
                                                        const int* __restrict__ src_sorted,
                                                        const float* __restrict__ inv_deg,
                                                        unsigned int* __restrict__ agg16) {
    int t = threadIdx.x;
    int wave = (blockIdx.x << 2) + (t >> 6);
    int lane = t & 63;
    int half = lane >> 5;
    int j = lane & 31;
    int node = (wave << 1) + half;
    if (node >= N_NODES) return;
    int s = row_start[node];
    int e = row_start[node + 1];
    float a0 = 0.f, a1 = 0.f, b0 = 0.f, b1 = 0.f;
    float c0 = 0.f, c1 = 0.f, d0 = 0.f, d1 = 0.f;
    int i = s;
    for (; i + 3 < e; i += 4) {
        int s0 = src_sorted[i], s1 = src_sorted[i + 1];
        int s2 = src_sorted[i + 2], s3 = src_sorted[i + 3];
        unsigned u0 = *(const unsigned*)(h16 + (size_t)s0 * H + 2 * j);
        unsigned u1 = *(const unsigned*)(h16 + (size_t)s1 * H + 2 * j);
        unsigned u2 = *(const unsigned*)(h16 + (size_t)s2 * H + 2 * j);
        unsigned u3 = *(const unsigned*)(h16 + (size_t)s3 * H + 2 * j);
        a0 += bflo(u0); a1 += bfhi(u0);
        b0 += bflo(u1); b1 += bfhi(u1);
        c0 += bflo(u2); c1 += bfhi(u2);
        d0 += bflo(u3); d1 += bfhi(u3);
    }
    for (; i < e; ++i) {
        unsigned u = *(const unsigned*)(h16 + (size_t)src_sorted[i] * H + 2 * j);
        a0 += bflo(u); a1 += bfhi(u);
    }
    float inv = inv_deg[node];
    float r0 = ((a0 + b0) + (c0 + d0)) * inv;
    float r1 = ((a1 + b1) + (c1 + d1)) * inv;
    agg16[(size_t)node * 32 + j] = (unsigned)f2bf(r0) | ((unsigned)f2bf(r1) << 16);
}

// ---------------------------------------------------------------------------
// SAGE update via MFMA: h16 = bf16(relu([agg|h] @ [Wl|Wr].T + bl) + h)
// Block = 16 nodes x 64 feats, 4 waves; wave w owns feats [w*16, w*16+16).
// A-frag (m97 gemm_bt pattern): row=lane&15, k=(lane>>4)*8+j (contiguous 16B).
// B-frag: W[f][k] row-major == B^T; f=lane&15(+f0), k=(lane>>4)*8+j.
// D: col(feat)=lane&15, row(node)=(lane>>4)*4+reg.
// All loads (frags + residual) BEFORE __syncthreads (drains vmcnt) -> in-place safe.
// ---------------------------------------------------------------------------

__global__ __launch_bounds__(256) void update_kernel(const float* __restrict__ Wl,
                                                     const float* __restrict__ bl,
                                                     const float* __restrict__ Wr,
                                                     const unsigned short* __restrict__ agg16,
                                                     unsigned short* __restrict__ h16) {
    int t = threadIdx.x;
    int w = t >> 6;
    int lane = t & 63;
    int r16 = lane & 15;
    int kc = lane >> 4;          // 0..3
    int nb = blockIdx.x * 16;
    int f0 = w * 16;

    const unsigned short* aRow = agg16 + (size_t)(nb + r16) * H;
    const unsigned short* hRow = h16 + (size_t)(nb + r16) * H;
    bf16x8 aA0 = ldfrag(aRow + kc * 8);
    bf16x8 aA1 = ldfrag(aRow + 32 + kc * 8);
    bf16x8 hA0 = ldfrag(hRow + kc * 8);
    bf16x8 hA1 = ldfrag(hRow + 32 + kc * 8);

    const float* wlRow = Wl + (size_t)(f0 + r16) * H;
    const float* wrRow = Wr + (size_t)(f0 + r16) * H;
    bf16x8 bL0 = cvt8(wlRow + kc * 8);
    bf16x8 bL1 = cvt8(wlRow + 32 + kc * 8);
    bf16x8 bR0 = cvt8(wrRow + kc * 8);
    bf16x8 bR1 = cvt8(wrRow + 32 + kc * 8);

    float bias = bl[f0 + r16];
    // residual: node = nb + kc*4 + j, feat = f0 + r16
    float hres[4];
    #pragma unroll
    for (int j = 0; j < 4; ++j)
        hres[j] = bfu(h16[(size_t)(nb + kc * 4 + j) * H + f0 + r16]);

    __syncthreads();   // all reads of h16 rows done before any store below

    f32x4 acc = {0.f, 0.f, 0.f, 0.f};
    acc = __builtin_amdgcn_mfma_f32_16x16x32_bf16(aA0, bL0, acc, 0, 0, 0);
    acc = __builtin_amdgcn_mfma_f32_16x16x32_bf16(aA1, bL1, acc, 0, 0, 0);
    acc = __builtin_amdgcn_mfma_f32_16x16x32_bf16(hA0, bR0, acc, 0, 0, 0);
    acc = __builtin_amdgcn_mfma_f32_16x16x32_bf16(hA1, bR1, acc, 0, 0, 0);

    #pragma unroll
    for (int j = 0; j < 4; ++j) {
        float v = fmaxf(acc[j] + bias, 0.f) + hres[j];
        h16[(size_t)(nb + kc * 4 + j) * H + f0 + r16] = f2bf(v);
    }
}

// ---------------------------------------------------------------------------
// Pool: 32 nodes/wave, same-graph fast path (batch sorted)
// ---------------------------------------------------------------------------

__global__ __launch_bounds__(256) void pool_kernel(const unsigned short* __restrict__ h16,
                                                   const int* __restrict__ batch,
                                                   float* __restrict__ gsum,
                                                   float* __restrict__ gcount) {
    int w = blockIdx.x * 4 + (threadIdx.x >> 6);
    int f = threadIdx.x & 63;
    int n0 = w * 32;
    if (n0 >= N_NODES) return;
    int n1 = min(n0 + 32, N_NODES);
    int g0 = batch[n0];
    int gend = batch[n1 - 1];
    if (g0 == gend) {
        float a0 = 0.f, a1 = 0.f, a2 = 0.f, a3 = 0.f;
        int n = n0;
        for (; n + 3 < n1; n += 4) {
            a0 += bfu(h16[(size_t)n * H + f]);
            a1 += bfu(h16[(size_t)(n + 1) * H + f]);
            a2 += bfu(h16[(size_t)(n + 2) * H + f]);
            a3 += bfu(h16[(size_t)(n + 3) * H + f]);
        }
        for (; n < n1; ++n) a0 += bfu(h16[(size_t)n * H + f]);
        atomicAdd(&gsum[g0 * H + f], (a0 + a1) + (a2 + a3));
        if (f == 0) atomicAdd(&gcount[g0], (float)(n1 - n0));
    } else {
        int curg = g0;
        float acc = 0.f;
        int cnt = 0;
        for (int n = n0; n < n1; ++n) {
            int g = batch[n];
            if (g != curg) {
                atomicAdd(&gsum[curg * H + f], acc);
                if (f == 0) atomicAdd(&gcount[curg], (float)cnt);
                acc = 0.f; cnt = 0; curg = g;
            }
            acc += bfu(h16[(size_t)n * H + f]);
            ++cnt;
        }
        atomicAdd(&gsum[curg * H + f], acc);
        if (f == 0) atomicAdd(&gcount[curg], (float)cnt);
    }
}

// ---------------------------------------------------------------------------
// Heads (unchanged)
// ---------------------------------------------------------------------------

__global__ __launch_bounds__(256) void policy_kernel(const float* __restrict__ gsum,
                                                     const float* __restrict__ gcount,
                                                     const float* __restrict__ Wp,
                                                     const float* __restrict__ bp,
                                                     float* __restrict__ out) {
    __shared__ float gr[H];
    int g = blockIdx.y;
    int t = threadIdx.x;
    if (t < H) {
        float inv = 1.0f / fmaxf(gcount[g], 1.0f);
        gr[t] = gsum[g * H + t] * inv;
    }
    __syncthreads();
    int a = blockIdx.x * 256 + t;
    if (a >= A_SZ) return;
    const float4* wp4 = (const float4*)(Wp + a * H);
    float acc = bp[a];
    #pragma unroll
    for (int c = 0; c < 16; ++c) {
        float4 wv = wp4[c];
        acc += gr[4 * c + 0] * wv.x + gr[4 * c + 1] * wv.y
             + gr[4 * c + 2] * wv.z + gr[4 * c + 3] * wv.w;
    }
    out[g * A_SZ + a] = acc;
}

__global__ void value_kernel(const float* __restrict__ gsum, const float* __restrict__ gcount,
                             const float* __restrict__ Wv, const float* __restrict__ bv,
                             float* __restrict__ out) {
    int g = threadIdx.x;
    if (g >= G_SZ) return;
    float inv = 1.0f / fmaxf(gcount[g], 1.0f);
    float acc = bv[0];
    #pragma unroll
    for (int k = 0; k < H; ++k) acc += gsum[g * H + k] * inv * Wv[k];
    out[G_SZ * A_SZ + g] = tanhf(acc);
}

// ---------------------------------------------------------------------------

extern "C" void kernel_launch(void* const* d_in, const int* in_sizes, int n_in,
                              void* d_out, int out_size, void* d_ws, size_t ws_size,
                              hipStream_t stream) {
    const float* x     = (const float*)d_in[0];
    const int*   ei    = (const int*)d_in[1];
    const int*   batch = (const int*)d_in[2];
    const float* W_enc = (const float*)d_in[3];
    const float* b_enc = (const float*)d_in[4];
    const float* Wl    = (const float*)d_in[5];
    const float* bl    = (const float*)d_in[6];
    const float* Wr    = (const float*)d_in[7];
    const float* Wp    = (const float*)d_in[8];
    const float* bp    = (const float*)d_in[9];
    const float* Wv    = (const float*)d_in[10];
    const float* bv    = (const float*)d_in[11];
    float* out = (float*)d_out;

    char* ws = (char*)d_ws;
    size_t off = 0;
    auto alloc = [&](size_t bytes) {
        char* p = ws + off;
        off = (off + bytes + 255) & ~(size_t)255;
        return p;
    };
    unsigned short* h16   = (unsigned short*)alloc((size_t)N_NODES * H * 2);
    unsigned int*   agg16 = (unsigned int*)alloc((size_t)N_NODES * H * 2);
    int* row_start        = (int*)alloc((size_t)(N_NODES + 1) * 4);
    float* inv_deg        = (float*)alloc((size_t)N_NODES * 4);
    int* src_sorted       = (int*)alloc((size_t)N_EDGES * 4);
    unsigned int* pairs   = (unsigned int*)alloc((size_t)N_EDGES * 4);
    int* bhist            = (int*)alloc((NBUCK + 8) * 4);
    int* bucket_base      = (int*)alloc((NBUCK + 8) * 4);
    int* bcursor          = (int*)alloc((NBUCK + 8) * 4);
    float* gsum           = (float*)alloc((size_t)(G_SZ * H + G_SZ) * 4);
    float* gcount         = gsum + G_SZ * H;

    // CSR build (bucketed)
    hipMemsetAsync(bhist, 0, NBUCK * 4, stream);
    bucket_hist_kernel<<<NEBLK, 256, 0, stream>>>(ei, bhist);
    bucket_scan_kernel<<<1, 512, 0, stream>>>(bhist, bucket_base, bcursor);
    bucket_scatter_kernel<<<NEBLK, 256, 0, stream>>>(ei, bcursor, pairs);
    bucket_rank_kernel<<<NBUCK, 256, 0, stream>>>(pairs, bucket_base, row_start,
                                                  inv_deg, src_sorted);

    encoder_kernel<<<N_NODES / 4, 256, 0, stream>>>(x, W_enc, b_enc, h16);

    const int UPD_BLOCKS = N_NODES / 16;  // 6250, exact
    for (int l = 0; l < L_LAYERS; ++l) {
        aggregate_kernel<<<N_NODES / 8, 256, 0, stream>>>(h16, row_start, src_sorted,
                                                          inv_deg, agg16);
        update_kernel<<<UPD_BLOCKS, 256, 0, stream>>>(Wl + (size_t)l * H * H, bl + l * H,
                                                      Wr + (size_t)l * H * H,
                                                      (const unsigned short*)agg16, h16);
    }

    hipMemsetAsync(gsum, 0, (size_t)(G_SZ * H + G_SZ) * 4, stream);
    const int POOL_BLOCKS = (N_NODES / 32 + 3) / 4 + 1;
    pool_kernel<<<POOL_BLOCKS, 256, 0, stream>>>(h16, batch, gsum, gcount);
    policy_kernel<<<dim3((A_SZ + 255) / 256, G_SZ), 256, 0, stream>>>(gsum, gcount, Wp, bp, out);
    value_kernel<<<1, 64, 0, stream>>>(gsum, gcount, Wv, bv, out);
}

// Round 7
// 604.641 us; speedup vs baseline: 11.1113x; 1.1056x over previous
//
#include <hip/hip_runtime.h>
#include <hip/hip_bf16.h>

#define N_NODES 100000
#define N_EDGES 3200000
#define F_IN    32
#define H       64
#define L_LAYERS 4
#define A_SZ    6158
#define G_SZ    64

#define NBUCK 391           // ceil(N_NODES / 256): bucket = dst >> 8
#define EPB   8192          // edges per block in bucket passes
#define NEBLK 391           // ceil(N_EDGES / EPB)

typedef __attribute__((ext_vector_type(8))) short bf16x8;
typedef __attribute__((ext_vector_type(4))) float f32x4;

__device__ __forceinline__ float bflo(unsigned u) { return __uint_as_float(u << 16); }
__device__ __forceinline__ float bfhi(unsigned u) { return __uint_as_float(u & 0xffff0000u); }
__device__ __forceinline__ float bfu(unsigned short u) { return __uint_as_float(((unsigned)u) << 16); }
__device__ __forceinline__ unsigned short f2bf(float f) {
    union { __hip_bfloat16 b; unsigned short u; } c;
    c.b = __float2bfloat16(f);
    return c.u;
}
__device__ __forceinline__ bf16x8 ldfrag(const unsigned short* p) {
    union { uint4 u; bf16x8 v; } c;
    c.u = *(const uint4*)p;
    return c.v;
}

#if __has_builtin(__builtin_amdgcn_make_buffer_rsrc) && __has_builtin(__builtin_amdgcn_raw_buffer_load_b32)
#define USE_BUFFER_LOAD 1
#else
#define USE_BUFFER_LOAD 0
#endif

// ---------------------------------------------------------------------------
// CSR build, bucketed. src_sorted holds PRE-SHIFTED byte offsets (src*128).
// ---------------------------------------------------------------------------

__global__ __launch_bounds__(256) void bucket_hist_kernel(const int* __restrict__ ei,
                                                          int* __restrict__ bhist) {
    __shared__ int hist[NBUCK];
    int t = threadIdx.x;
    for (int i = t; i < NBUCK; i += 256) hist[i] = 0;
    __syncthreads();
    int base = blockIdx.x * EPB;
    #pragma unroll
    for (int i = 0; i < EPB / 256; ++i) {
        int e = base + i * 256 + t;
        if (e < N_EDGES) atomicAdd(&hist[ei[N_EDGES + e] >> 8], 1);
    }
    __syncthreads();
    for (int i = t; i < NBUCK; i += 256)
        if (hist[i]) atomicAdd(&bhist[i], hist[i]);
}

__global__ void bucket_scan_kernel(const int* __restrict__ bhist,
                                   int* __restrict__ bucket_base,
                                   int* __restrict__ bcursor) {
    __shared__ int s[512];
    int t = threadIdx.x;
    int v = (t < NBUCK) ? bhist[t] : 0;
    s[t] = v;
    __syncthreads();
    for (int off = 1; off < 512; off <<= 1) {
        int x = (t >= off) ? s[t - off] : 0;
        __syncthreads();
        s[t] += x;
        __syncthreads();
    }
    if (t < NBUCK) {
        int excl = s[t] - v;
        bucket_base[t] = excl;
        bcursor[t] = excl;
    }
    if (t == 0) bucket_base[NBUCK] = N_EDGES;
}

__global__ __launch_bounds__(256) void bucket_scatter_kernel(const int* __restrict__ ei,
                                                             int* __restrict__ bcursor,
                                                             unsigned int* __restrict__ pairs) {
    __shared__ int hist[NBUCK];
    __shared__ int cur[NBUCK];
    int t = threadIdx.x;
    for (int i = t; i < NBUCK; i += 256) hist[i] = 0;
    __syncthreads();
    int base = blockIdx.x * EPB;
    #pragma unroll
    for (int i = 0; i < EPB / 256; ++i) {
        int e = base + i * 256 + t;
        if (e < N_EDGES) atomicAdd(&hist[ei[N_EDGES + e] >> 8], 1);
    }
    __syncthreads();
    for (int i = t; i < NBUCK; i += 256) {
        int c = hist[i];
        cur[i] = c ? atomicAdd(&bcursor[i], c) : 0;
    }
    __syncthreads();
    #pragma unroll
    for (int i = 0; i < EPB / 256; ++i) {
        int e = base + i * 256 + t;
        if (e < N_EDGES) {
            int src = ei[e];
            int dst = ei[N_EDGES + e];
            int b = dst >> 8;
            int idx = atomicAdd(&cur[b], 1);
            pairs[idx] = ((unsigned int)(dst & 255) << 17) | (unsigned int)src;
        }
    }
}

__global__ __launch_bounds__(256) void bucket_rank_kernel(const unsigned int* __restrict__ pairs,
                                                          const int* __restrict__ bucket_base,
                                                          int* __restrict__ row_start,
                                                          float* __restrict__ inv_deg,
                                                          int* __restrict__ src_sorted) {
    __shared__ int cnt[256];
    __shared__ int scn[256];
    __shared__ int cur[256];
    int b = blockIdx.x;
    int t = threadIdx.x;
    int nb0 = b << 8;
    int e0 = bucket_base[b];
    int e1 = bucket_base[b + 1];
    cnt[t] = 0;
    __syncthreads();
    for (int e = e0 + t; e < e1; e += 256)
        atomicAdd(&cnt[pairs[e] >> 17], 1);
    __syncthreads();
    int v = cnt[t];
    scn[t] = v;
    __syncthreads();
    for (int off = 1; off < 256; off <<= 1) {
        int x = (t >= off) ? scn[t - off] : 0;
        __syncthreads();
        scn[t] += x;
        __syncthreads();
    }
    int excl = scn[t] - v;
    int n = nb0 + t;
    if (n < N_NODES) {
        row_start[n] = e0 + excl;
        inv_deg[n] = 1.0f / (float)max(v, 1);
    }
    cur[t] = e0 + excl;
    __syncthreads();
    for (int e = e0 + t; e < e1; e += 256) {
        unsigned int p = pairs[e];
        int slot = atomicAdd(&cur[p >> 17], 1);
        src_sorted[slot] = (int)((p & 0x1FFFFu) << 7);   // pre-shifted: src*128
    }
    if (b == 0 && t == 0) row_start[N_NODES] = N_EDGES;
}

// ---------------------------------------------------------------------------
// Weight pre-convert: Wl/Wr (all layers) fp32 -> bf16, once per launch
// ---------------------------------------------------------------------------

__global__ __launch_bounds__(256) void wconv_kernel(const float* __restrict__ Wl,
                                                    const float* __restrict__ Wr,
                                                    unsigned short* __restrict__ wl16,
                                                    unsigned short* __restrict__ wr16) {
    int i = blockIdx.x * 256 + threadIdx.x;   // L*H*H = 16384 total
    wl16[i] = f2bf(Wl[i]);
    wr16[i] = f2bf(Wr[i]);
}

// ---------------------------------------------------------------------------
// Encoder: h16 = bf16(relu(x @ W_enc.T + b_enc))
// ---------------------------------------------------------------------------

__global__ __launch_bounds__(256) void encoder_kernel(const float* __restrict__ x,
                                                      const float* __restrict__ W_enc,
                                                      const float* __restrict__ b_enc,
                                                      unsigned short* __restrict__ h16) {
    __shared__ float Wt[F_IN][H + 1];
    __shared__ float xl[4][F_IN];
    int t = threadIdx.x;
    #pragma unroll
    for (int r = 0; r < 8; ++r) {
        int idx = r * 256 + t;
        Wt[idx & 31][idx >> 5] = W_enc[idx];
    }
    int nb = blockIdx.x * 4;
    if (t < 128) ((float*)xl)[t] = x[nb * F_IN + t];
    __syncthreads();
    int n = t >> 6;
    int f = t & 63;
    float acc = b_enc[f];
    #pragma unroll
    for (int k = 0; k < F_IN; ++k) acc += xl[n][k] * Wt[k][f];
    h16[(size_t)(nb + n) * H + f] = f2bf(fmaxf(acc, 0.0f));
}

// ---------------------------------------------------------------------------
// Aggregate: mean of h16 rows over incoming neighbors -> bf16 agg16.
// 2 nodes/wave (32 lanes each, lane j = feats 2j,2j+1). src_sorted is
// pre-shifted byte offsets; gathers use 32-bit voffset buffer loads.
// ---------------------------------------------------------------------------

__global__ __launch_bounds__(256) void aggregate_kernel(const unsigned short* __restrict__ h16,
                                                        const int* __restrict__ row_start,
                                                        const int* __restrict__ src_sorted,
                                                        const float* __restrict__ inv_deg,
                                                        unsigned int* __restrict__ agg16) {
    int t = threadIdx.x;
    int wave = (blockIdx.x << 2) + (t >> 6);
    int lane = t & 63;
    int half = lane >> 5;
    int j = lane & 31;
    int node = (wave << 1) + half;
    if (node >= N_NODES) return;
    int s = row_start[node];
    int e = row_start[node + 1];
    int off = 4 * j;

#if USE_BUFFER_LOAD
    __amdgpu_buffer_rsrc_t rs = __builtin_amdgcn_make_buffer_rsrc(
        (void*)h16, (short)0, (int)((size_t)N_NODES * 128), 0x00020000);
    #define GATHER(vo) __builtin_amdgcn_raw_buffer_load_b32(rs, (vo) + off, 0, 0)
#else
    const char* hb = (const char*)h16;
    #define GATHER(vo) (*(const unsigned*)(hb + (size_t)(unsigned)((vo) + off)))
#endif

    float a0 = 0.f, a1 = 0.f, b0 = 0.f, b1 = 0.f;
    float c0 = 0.f, c1 = 0.f, d0 = 0.f, d1 = 0.f;
    int i = s;
    for (; i + 7 < e; i += 8) {
        int s0 = src_sorted[i],     s1 = src_sorted[i + 1];
        int s2 = src_sorted[i + 2], s3 = src_sorted[i + 3];
        int s4 = src_sorted[i + 4], s5 = src_sorted[i + 5];
        int s6 = src_sorted[i + 6], s7 = src_sorted[i + 7];
        unsigned u0 = GATHER(s0), u1 = GATHER(s1);
        unsigned u2 = GATHER(s2), u3 = GATHER(s3);
        unsigned u4 = GATHER(s4), u5 = GATHER(s5);
        unsigned u6 = GATHER(s6), u7 = GATHER(s7);
        a0 += bflo(u0); a1 += bfhi(u0);
        b0 += bflo(u1); b1 += bfhi(u1);
        c0 += bflo(u2); c1 += bfhi(u2);
        d0 += bflo(u3); d1 += bfhi(u3);
        a0 += bflo(u4); a1 += bfhi(u4);
        b0 += bflo(u5); b1 += bfhi(u5);
        c0 += bflo(u6); c1 += bfhi(u6);
        d0 += bflo(u7); d1 += bfhi(u7);
    }
    for (; i < e; ++i) {
        unsigned u = GATHER(src_sorted[i]);
        a0 += bflo(u); a1 += bfhi(u);
    }
    #undef GATHER
    float inv = inv_deg[node];
    float r0 = ((a0 + b0) + (c0 + d0)) * inv;
    float r1 = ((a1 + b1) + (c1 + d1)) * inv;
    agg16[(size_t)node * 32 + j] = (unsigned)f2bf(r0) | ((unsigned)f2bf(r1) << 16);
}

// ---------------------------------------------------------------------------
// SAGE update via MFMA: h16 = bf16(relu([agg|h] @ [Wl|Wr].T + bl) + h)
// Block = 16 nodes x 64 feats, 4 waves; weights pre-converted bf16.
// ---------------------------------------------------------------------------

__global__ __launch_bounds__(256) void update_kernel(const unsigned short* __restrict__ wl16,
                                                     const float* __restrict__ bl,
                                                     const unsigned short* __restrict__ wr16,
                                                     const unsigned short* __restrict__ agg16,
                                                     unsigned short* __restrict__ h16) {
    int t = threadIdx.x;
    int w = t >> 6;
    int lane = t & 63;
    int r16 = lane & 15;
    int kc = lane >> 4;          // 0..3
    int nb = blockIdx.x * 16;
    int f0 = w * 16;

    const unsigned short* aRow = agg16 + (size_t)(nb + r16) * H;
    const unsigned short* hRow = h16 + (size_t)(nb + r16) * H;
    bf16x8 aA0 = ldfrag(aRow + kc * 8);
    bf16x8 aA1 = ldfrag(aRow + 32 + kc * 8);
    bf16x8 hA0 = ldfrag(hRow + kc * 8);
    bf16x8 hA1 = ldfrag(hRow + 32 + kc * 8);

    const unsigned short* wlRow = wl16 + (size_t)(f0 + r16) * H;
    const unsigned short* wrRow = wr16 + (size_t)(f0 + r16) * H;
    bf16x8 bL0 = ldfrag(wlRow + kc * 8);
    bf16x8 bL1 = ldfrag(wlRow + 32 + kc * 8);
    bf16x8 bR0 = ldfrag(wrRow + kc * 8);
    bf16x8 bR1 = ldfrag(wrRow + 32 + kc * 8);

    float bias = bl[f0 + r16];
    float hres[4];
    #pragma unroll
    for (int jq = 0; jq < 4; ++jq)
        hres[jq] = bfu(h16[(size_t)(nb + kc * 4 + jq) * H + f0 + r16]);

    __syncthreads();   // all reads of h16 rows complete before any store

    f32x4 acc = {0.f, 0.f, 0.f, 0.f};
    acc = __builtin_amdgcn_mfma_f32_16x16x32_bf16(aA0, bL0, acc, 0, 0, 0);
    acc = __builtin_amdgcn_mfma_f32_16x16x32_bf16(aA1, bL1, acc, 0, 0, 0);
    acc = __builtin_amdgcn_mfma_f32_16x16x32_bf16(hA0, bR0, acc, 0, 0, 0);
    acc = __builtin_amdgcn_mfma_f32_16x16x32_bf16(hA1, bR1, acc, 0, 0, 0);

    #pragma unroll
    for (int jq = 0; jq < 4; ++jq) {
        float v = fmaxf(acc[jq] + bias, 0.f) + hres[jq];
        h16[(size_t)(nb + kc * 4 + jq) * H + f0 + r16] = f2bf(v);
    }
}

// ---------------------------------------------------------------------------
// Pool: 32 nodes/wave, same-graph fast path (batch sorted)
// ---------------------------------------------------------------------------

__global__ __launch_bounds__(256) void pool_kernel(const unsigned short* __restrict__ h16,
                                                   const int* __restrict__ batch,
                                                   float* __restrict__ gsum,
                                                   float* __restrict__ gcount) {
    int w = blockIdx.x * 4 + (threadIdx.x >> 6);
    int f = threadIdx.x & 63;
    int n0 = w * 32;
    if (n0 >= N_NODES) return;
    int n1 = min(n0 + 32, N_NODES);
    int g0 = batch[n0];
    int gend = batch[n1 - 1];
    if (g0 == gend) {
        float a0 = 0.f, a1 = 0.f, a2 = 0.f, a3 = 0.f;
        int n = n0;
        for (; n + 3 < n1; n += 4) {
            a0 += bfu(h16[(size_t)n * H + f]);
            a1 += bfu(h16[(size_t)(n + 1) * H + f]);
            a2 += bfu(h16[(size_t)(n + 2) * H + f]);
            a3 += bfu(h16[(size_t)(n + 3) * H + f]);
        }
        for (; n < n1; ++n) a0 += bfu(h16[(size_t)n * H + f]);
        atomicAdd(&gsum[g0 * H + f], (a0 + a1) + (a2 + a3));
        if (f == 0) atomicAdd(&gcount[g0], (float)(n1 - n0));
    } else {
        int curg = g0;
        float acc = 0.f;
        int cnt = 0;
        for (int n = n0; n < n1; ++n) {
            int g = batch[n];
            if (g != curg) {
                atomicAdd(&gsum[curg * H + f], acc);
                if (f == 0) atomicAdd(&gcount[curg], (float)cnt);
                acc = 0.f; cnt = 0; curg = g;
            }
            acc += bfu(h16[(size_t)n * H + f]);
            ++cnt;
        }
        atomicAdd(&gsum[curg * H + f], acc);
        if (f == 0) atomicAdd(&gcount[curg], (float)cnt);
    }
}

// ---------------------------------------------------------------------------
// Heads: policy handles 8 graphs per block (Wp re-read 8x instead of 64x)
// ---------------------------------------------------------------------------

__global__ __launch_bounds__(256) void policy_kernel(const float* __restrict__ gsum,
                                                     const float* __restrict__ gcount,
                                                     const float* __restrict__ Wp,
                                                     const float* __restrict__ bp,
                                                     float* __restrict__ out) {
    __shared__ float gr[8][H];
    int g0 = blockIdx.y * 8;
    int t = threadIdx.x;
    #pragma unroll
    for (int r = 0; r < 2; ++r) {
        int idx = r * 256 + t;
        int gg = idx >> 6, f = idx & 63;
        float inv = 1.0f / fmaxf(gcount[g0 + gg], 1.0f);
        gr[gg][f] = gsum[(g0 + gg) * H + f] * inv;
    }
    __syncthreads();
    int a = blockIdx.x * 256 + t;
    if (a >= A_SZ) return;
    const float4* wp4 = (const float4*)(Wp + a * H);
    float bpa = bp[a];
    float acc[8];
    #pragma unroll
    for (int gg = 0; gg < 8; ++gg) acc[gg] = bpa;
    #pragma unroll
    for (int c = 0; c < 16; ++c) {
        float4 wv = wp4[c];
        #pragma unroll
        for (int gg = 0; gg < 8; ++gg) {
            acc[gg] += gr[gg][4 * c + 0] * wv.x + gr[gg][4 * c + 1] * wv.y
                     + gr[gg][4 * c + 2] * wv.z + gr[gg][4 * c + 3] * wv.w;
        }
    }
    #pragma unroll
    for (int gg = 0; gg < 8; ++gg)
        out[(g0 + gg) * A_SZ + a] = acc[gg];
}

__global__ void value_kernel(const float* __restrict__ gsum, const float* __restrict__ gcount,
                             const float* __restrict__ Wv, const float* __restrict__ bv,
                             float* __restrict__ out) {
    int g = threadIdx.x;
    if (g >= G_SZ) return;
    float inv = 1.0f / fmaxf(gcount[g], 1.0f);
    float acc = bv[0];
    #pragma unroll
    for (int k = 0; k < H; ++k) acc += gsum[g * H + k] * inv * Wv[k];
    out[G_SZ * A_SZ + g] = tanhf(acc);
}

// ---------------------------------------------------------------------------

extern "C" void kernel_launch(void* const* d_in, const int* in_sizes, int n_in,
                              void* d_out, int out_size, void* d_ws, size_t ws_size,
                              hipStream_t stream) {
    const float* x     = (const float*)d_in[0];
    const int*   ei    = (const int*)d_in[1];
    const int*   batch = (const int*)d_in[2];
    const float* W_enc = (const float*)d_in[3];
    const float* b_enc = (const float*)d_in[4];
    const float* Wl    = (const float*)d_in[5];
    const float* bl    = (const float*)d_in[6];
    const float* Wr    = (const float*)d_in[7];
    const float* Wp    = (const float*)d_in[8];
    const float* bp    = (const float*)d_in[9];
    const float* Wv    = (const float*)d_in[10];
    const float* bv    = (const float*)d_in[11];
    float* out = (float*)d_out;

    char* ws = (char*)d_ws;
    size_t off = 0;
    auto alloc = [&](size_t bytes) {
        char* p = ws + off;
        off = (off + bytes + 255) & ~(size_t)255;
        return p;
    };
    unsigned short* h16   = (unsigned short*)alloc((size_t)N_NODES * H * 2);
    unsigned int*   agg16 = (unsigned int*)alloc((size_t)N_NODES * H * 2);
    int* row_start        = (int*)alloc((size_t)(N_NODES + 1) * 4);
    float* inv_deg        = (float*)alloc((size_t)N_NODES * 4);
    int* src_sorted       = (int*)alloc((size_t)N_EDGES * 4);
    unsigned int* pairs   = (unsigned int*)alloc((size_t)N_EDGES * 4);
    int* bhist            = (int*)alloc((NBUCK + 8) * 4);
    int* bucket_base      = (int*)alloc((NBUCK + 8) * 4);
    int* bcursor          = (int*)alloc((NBUCK + 8) * 4);
    unsigned short* wl16  = (unsigned short*)alloc((size_t)L_LAYERS * H * H * 2);
    unsigned short* wr16  = (unsigned short*)alloc((size_t)L_LAYERS * H * H * 2);
    float* gsum           = (float*)alloc((size_t)(G_SZ * H + G_SZ) * 4);
    float* gcount         = gsum + G_SZ * H;

    // CSR build (bucketed)
    hipMemsetAsync(bhist, 0, NBUCK * 4, stream);
    bucket_hist_kernel<<<NEBLK, 256, 0, stream>>>(ei, bhist);
    bucket_scan_kernel<<<1, 512, 0, stream>>>(bhist, bucket_base, bcursor);
    bucket_scatter_kernel<<<NEBLK, 256, 0, stream>>>(ei, bcursor, pairs);
    bucket_rank_kernel<<<NBUCK, 256, 0, stream>>>(pairs, bucket_base, row_start,
                                                  inv_deg, src_sorted);

    wconv_kernel<<<(L_LAYERS * H * H) / 256, 256, 0, stream>>>(Wl, Wr, wl16, wr16);
    encoder_kernel<<<N_NODES / 4, 256, 0, stream>>>(x, W_enc, b_enc, h16);

    const int UPD_BLOCKS = N_NODES / 16;  // 6250, exact
    for (int l = 0; l < L_LAYERS; ++l) {
        aggregate_kernel<<<N_NODES / 8, 256, 0, stream>>>(h16, row_start, src_sorted,
                                                          inv_deg, agg16);
        update_kernel<<<UPD_BLOCKS, 256, 0, stream>>>(wl16 + (size_t)l * H * H, bl + l * H,
                                                      wr16 + (size_t)l * H * H,
                                                      (const unsigned short*)agg16, h16);
    }

    hipMemsetAsync(gsum, 0, (size_t)(G_SZ * H + G_SZ) * 4, stream);
    const int POOL_BLOCKS = (N_NODES / 32 + 3) / 4 + 1;
    pool_kernel<<<POOL_BLOCKS, 256, 0, stream>>>(h16, batch, gsum, gcount);
    policy_kernel<<<dim3((A_SZ + 255) / 256, 8), 256, 0, stream>>>(gsum, gcount, Wp, bp, out);
    value_kernel<<<1, 64, 0, stream>>>(gsum, gcount, Wv, bv, out);
}

// Round 9
// 553.414 us; speedup vs baseline: 12.1399x; 1.0926x over previous
//
#include <hip/hip_runtime.h>
#include <hip/hip_bf16.h>

#define N_NODES 100000
#define N_EDGES 3200000
#define F_IN    32
#define H       64
#define L_LAYERS 4
#define A_SZ    6158
#define G_SZ    64

#define NBUCK 391           // ceil(N_NODES / 256): bucket = dst >> 8
#define EPB   4096          // edges per block in bucket passes
#define NEBLK 782           // ceil(N_EDGES / EPB)
#define ROW_SHIFT 6         // h8 row = 64 bytes

#define VMAXQ 32.0f
#define QENC  7.96875f            // 255/32
#define QDEC  (32.0f / 255.0f)

typedef __attribute__((ext_vector_type(8))) short bf16x8;
typedef __attribute__((ext_vector_type(4))) float f32x4;

__device__ __forceinline__ float bflo(unsigned u) { return __uint_as_float(u << 16); }
__device__ __forceinline__ float bfhi(unsigned u) { return __uint_as_float(u & 0xffff0000u); }
__device__ __forceinline__ float bfu(unsigned short u) { return __uint_as_float(((unsigned)u) << 16); }
__device__ __forceinline__ unsigned short f2bf(float f) {
    union { __hip_bfloat16 b; unsigned short u; } c;
    c.b = __float2bfloat16(f);
    return c.u;
}
__device__ __forceinline__ unsigned char f2u8(float v) {
    return (unsigned char)(fminf(v, VMAXQ) * QENC + 0.5f);   // v >= 0 always
}
__device__ __forceinline__ bf16x8 ldfrag(const unsigned short* p) {
    union { uint4 u; bf16x8 v; } c;
    c.u = *(const uint4*)p;
    return c.v;
}

#if __has_builtin(__builtin_amdgcn_make_buffer_rsrc) && __has_builtin(__builtin_amdgcn_raw_buffer_load_b32)
#define USE_BUFFER_LOAD 1
#else
#define USE_BUFFER_LOAD 0
#endif

// ---------------------------------------------------------------------------
// CSR build, bucketed. src_sorted holds PRE-SHIFTED byte offsets (src*64).
// ---------------------------------------------------------------------------

__global__ __launch_bounds__(256) void bucket_hist_kernel(const int* __restrict__ ei,
                                                          int* __restrict__ bhist) {
    __shared__ int hist[NBUCK];
    int t = threadIdx.x;
    for (int i = t; i < NBUCK; i += 256) hist[i] = 0;
    __syncthreads();
    int base = blockIdx.x * EPB;
    #pragma unroll
    for (int i = 0; i < EPB / 256; ++i) {
        int e = base + i * 256 + t;
        if (e < N_EDGES) atomicAdd(&hist[ei[N_EDGES + e] >> 8], 1);
    }
    __syncthreads();
    for (int i = t; i < NBUCK; i += 256)
        if (hist[i]) atomicAdd(&bhist[i], hist[i]);
}

__global__ void bucket_scan_kernel(const int* __restrict__ bhist,
                                   int* __restrict__ bucket_base,
                                   int* __restrict__ bcursor) {
    __shared__ int s[512];
    int t = threadIdx.x;
    int v = (t < NBUCK) ? bhist[t] : 0;
    s[t] = v;
    __syncthreads();
    for (int off = 1; off < 512; off <<= 1) {
        int x = (t >= off) ? s[t - off] : 0;
        __syncthreads();
        s[t] += x;
        __syncthreads();
    }
    if (t < NBUCK) {
        int excl = s[t] - v;
        bucket_base[t] = excl;
        bcursor[t] = excl;
    }
    if (t == 0) bucket_base[NBUCK] = N_EDGES;
}

__global__ __launch_bounds__(256) void bucket_scatter_kernel(const int* __restrict__ ei,
                                                             int* __restrict__ bcursor,
                                                             unsigned int* __restrict__ pairs) {
    __shared__ int hist[NBUCK];
    __shared__ int cur[NBUCK];
    int t = threadIdx.x;
    for (int i = t; i < NBUCK; i += 256) hist[i] = 0;
    __syncthreads();
    int base = blockIdx.x * EPB;
    #pragma unroll
    for (int i = 0; i < EPB / 256; ++i) {
        int e = base + i * 256 + t;
        if (e < N_EDGES) atomicAdd(&hist[ei[N_EDGES + e] >> 8], 1);
    }
    __syncthreads();
    for (int i = t; i < NBUCK; i += 256) {
        int c = hist[i];
        cur[i] = c ? atomicAdd(&bcursor[i], c) : 0;
    }
    __syncthreads();
    #pragma unroll
    for (int i = 0; i < EPB / 256; ++i) {
        int e = base + i * 256 + t;
        if (e < N_EDGES) {
            int src = ei[e];
            int dst = ei[N_EDGES + e];
            int b = dst >> 8;
            int idx = atomicAdd(&cur[b], 1);
            pairs[idx] = ((unsigned int)(dst & 255) << 17) | (unsigned int)src;
        }
    }
}

__global__ __launch_bounds__(256) void bucket_rank_kernel(const unsigned int* __restrict__ pairs,
                                                          const int* __restrict__ bucket_base,
                                                          int* __restrict__ row_start,
                                                          float* __restrict__ inv_deg,
                                                          int* __restrict__ src_sorted) {
    __shared__ int cnt[256];
    __shared__ int scn[256];
    __shared__ int cur[256];
    int b = blockIdx.x;
    int t = threadIdx.x;
    int nb0 = b << 8;
    int e0 = bucket_base[b];
    int e1 = bucket_base[b + 1];
    cnt[t] = 0;
    __syncthreads();
    for (int e = e0 + t; e < e1; e += 256)
        atomicAdd(&cnt[pairs[e] >> 17], 1);
    __syncthreads();
    int v = cnt[t];
    scn[t] = v;
    __syncthreads();
    for (int off = 1; off < 256; off <<= 1) {
        int x = (t >= off) ? scn[t - off] : 0;
        __syncthreads();
        scn[t] += x;
        __syncthreads();
    }
    int excl = scn[t] - v;
    int n = nb0 + t;
    if (n < N_NODES) {
        row_start[n] = e0 + excl;
        inv_deg[n] = 1.0f / (float)max(v, 1);
    }
    cur[t] = e0 + excl;
    __syncthreads();
    for (int e = e0 + t; e < e1; e += 256) {
        unsigned int p = pairs[e];
        int slot = atomicAdd(&cur[p >> 17], 1);
        src_sorted[slot] = (int)((p & 0x1FFFFu) << ROW_SHIFT);
    }
    if (b == 0 && t == 0) row_start[N_NODES] = N_EDGES;
}

// ---------------------------------------------------------------------------
// Weight pre-convert: Wl/Wr (all layers) fp32 -> bf16, once per launch
// ---------------------------------------------------------------------------

__global__ __launch_bounds__(256) void wconv_kernel(const float* __restrict__ Wl,
                                                    const float* __restrict__ Wr,
                                                    unsigned short* __restrict__ wl16,
                                                    unsigned short* __restrict__ wr16) {
    int i = blockIdx.x * 256 + threadIdx.x;   // L*H*H = 16384 total
    wl16[i] = f2bf(Wl[i]);
    wr16[i] = f2bf(Wr[i]);
}

// ---------------------------------------------------------------------------
// Encoder: h16 = bf16(relu(x @ W_enc.T + b_enc)); u8 mirror h8
// ---------------------------------------------------------------------------

__global__ __launch_bounds__(256) void encoder_kernel(const float* __restrict__ x,
                                                      const float* __restrict__ W_enc,
                                                      const float* __restrict__ b_enc,
                                                      unsigned short* __restrict__ h16,
                                                      unsigned char* __restrict__ h8) {
    __shared__ float Wt[F_IN][H + 1];
    __shared__ float xl[4][F_IN];
    int t = threadIdx.x;
    #pragma unroll
    for (int r = 0; r < 8; ++r) {
        int idx = r * 256 + t;
        Wt[idx & 31][idx >> 5] = W_enc[idx];
    }
    int nb = blockIdx.x * 4;
    if (t < 128) ((float*)xl)[t] = x[nb * F_IN + t];
    __syncthreads();
    int n = t >> 6;
    int f = t & 63;
    float acc = b_enc[f];
    #pragma unroll
    for (int k = 0; k < F_IN; ++k) acc += xl[n][k] * Wt[k][f];
    float v = fmaxf(acc, 0.0f);
    h16[(size_t)(nb + n) * H + f] = f2bf(v);
    h8[(size_t)(nb + n) * H + f] = f2u8(v);
}

// ---------------------------------------------------------------------------
// Aggregate: mean over incoming neighbors -> bf16 agg16.
// u8 path: 4 nodes/wave, 16 lanes/row, 1 dword = 4 u8 feats per lane.
// Decode (float)(byte) -> v_cvt_f32_ubyteN; scale folded into inv_deg*QDEC.
// ---------------------------------------------------------------------------

__global__ __launch_bounds__(256) void aggregate_kernel(const unsigned char* __restrict__ h8,
                                                        const int* __restrict__ row_start,
                                                        const int* __restrict__ src_sorted,
                                                        const float* __restrict__ inv_deg,
                                                        unsigned int* __restrict__ agg16) {
    int t = threadIdx.x;
    int wave = (blockIdx.x << 2) + (t >> 6);
    int lane = t & 63;
    int q = lane >> 4;           // node within wave
    int j = lane & 15;           // dword within 64 B row
    int node = (wave << 2) + q;
    int s = row_start[node];
    int e = row_start[node + 1];
    int off = 4 * j;

#if USE_BUFFER_LOAD
    __amdgpu_buffer_rsrc_t rs = __builtin_amdgcn_make_buffer_rsrc(
        (void*)h8, (short)0, (int)((size_t)N_NODES * 64), 0x00020000);
    #define GATHER8(vo) ((unsigned)__builtin_amdgcn_raw_buffer_load_b32(rs, (vo) + off, 0, 0))
#else
    #define GATHER8(vo) (*(const unsigned*)(h8 + (size_t)(unsigned)((vo) + off)))
#endif

    float a0 = 0.f, a1 = 0.f, a2 = 0.f, a3 = 0.f;
    float b0 = 0.f, b1 = 0.f, b2 = 0.f, b3 = 0.f;

    #define ACCU(u, x0, x1, x2, x3) { \
        x0 += (float)((u) & 255u); \
        x1 += (float)(((u) >> 8) & 255u); \
        x2 += (float)(((u) >> 16) & 255u); \
        x3 += (float)((u) >> 24); }

    int i = s;
    for (; i + 7 < e; i += 8) {
        int s0 = src_sorted[i],     s1 = src_sorted[i + 1];
        int s2 = src_sorted[i + 2], s3 = src_sorted[i + 3];
        int s4 = src_sorted[i + 4], s5 = src_sorted[i + 5];
        int s6 = src_sorted[i + 6], s7 = src_sorted[i + 7];
        unsigned u0 = GATHER8(s0), u1 = GATHER8(s1);
        unsigned u2 = GATHER8(s2), u3 = GATHER8(s3);
        unsigned u4 = GATHER8(s4), u5 = GATHER8(s5);
        unsigned u6 = GATHER8(s6), u7 = GATHER8(s7);
        ACCU(u0, a0, a1, a2, a3)
        ACCU(u1, b0, b1, b2, b3)
        ACCU(u2, a0, a1, a2, a3)
        ACCU(u3, b0, b1, b2, b3)
        ACCU(u4, a0, a1, a2, a3)
        ACCU(u5, b0, b1, b2, b3)
        ACCU(u6, a0, a1, a2, a3)
        ACCU(u7, b0, b1, b2, b3)
    }
    for (; i < e; ++i) {
        unsigned u = GATHER8(src_sorted[i]);
        ACCU(u, a0, a1, a2, a3)
    }
    #undef ACCU
    #undef GATHER8
    float sc = inv_deg[node] * QDEC;
    float r0 = (a0 + b0) * sc, r1 = (a1 + b1) * sc;
    float r2 = (a2 + b2) * sc, r3 = (a3 + b3) * sc;
    unsigned p0 = (unsigned)f2bf(r0) | ((unsigned)f2bf(r1) << 16);
    unsigned p1 = (unsigned)f2bf(r2) | ((unsigned)f2bf(r3) << 16);
    *(uint2*)(agg16 + ((size_t)node << 5) + 2 * j) = make_uint2(p0, p1);
}

// ---------------------------------------------------------------------------
// SAGE update via MFMA: h16 = bf16(relu([agg|h] @ [Wl|Wr].T + bl) + h); u8 mirror
// Block = 16 nodes x 64 feats, 4 waves; all loads before __syncthreads.
// ---------------------------------------------------------------------------

__global__ __launch_bounds__(256) void update_kernel(const unsigned short* __restrict__ wl16,
                                                     const float* __restrict__ bl,
                                                     const unsigned short* __restrict__ wr16,
                                                     const unsigned short* __restrict__ agg16,
                                                     unsigned short* __restrict__ h16,
                                                     unsigned char* __restrict__ h8) {
    int t = threadIdx.x;
    int w = t >> 6;
    int lane = t & 63;
    int r16 = lane & 15;
    int kc = lane >> 4;          // 0..3
    int nb = blockIdx.x * 16;
    int f0 = w * 16;

    const unsigned short* aRow = agg16 + (size_t)(nb + r16) * H;
    const unsigned short* hRow = h16 + (size_t)(nb + r16) * H;
    bf16x8 aA0 = ldfrag(aRow + kc * 8);
    bf16x8 aA1 = ldfrag(aRow + 32 + kc * 8);
    bf16x8 hA0 = ldfrag(hRow + kc * 8);
    bf16x8 hA1 = ldfrag(hRow + 32 + kc * 8);

    const unsigned short* wlRow = wl16 + (size_t)(f0 + r16) * H;
    const unsigned short* wrRow = wr16 + (size_t)(f0 + r16) * H;
    bf16x8 bL0 = ldfrag(wlRow + kc * 8);
    bf16x8 bL1 = ldfrag(wlRow + 32 + kc * 8);
    bf16x8 bR0 = ldfrag(wrRow + kc * 8);
    bf16x8 bR1 = ldfrag(wrRow + 32 + kc * 8);

    float bias = bl[f0 + r16];
    float hres[4];
    #pragma unroll
    for (int jq = 0; jq < 4; ++jq)
        hres[jq] = bfu(h16[(size_t)(nb + kc * 4 + jq) * H + f0 + r16]);

    __syncthreads();   // all reads of h16 rows complete before any store

    f32x4 acc = {0.f, 0.f, 0.f, 0.f};
    acc = __builtin_amdgcn_mfma_f32_16x16x32_bf16(aA0, bL0, acc, 0, 0, 0);
    acc = __builtin_amdgcn_mfma_f32_16x16x32_bf16(aA1, bL1, acc, 0, 0, 0);
    acc = __builtin_amdgcn_mfma_f32_16x16x32_bf16(hA0, bR0, acc, 0, 0, 0);
    acc = __builtin_amdgcn_mfma_f32_16x16x32_bf16(hA1, bR1, acc, 0, 0, 0);

    #pragma unroll
    for (int jq = 0; jq < 4; ++jq) {
        float v = fmaxf(acc[jq] + bias, 0.f) + hres[jq];
        size_t o = (size_t)(nb + kc * 4 + jq) * H + f0 + r16;
        h16[o] = f2bf(v);
        h8[o] = f2u8(v);
    }
}

// ---------------------------------------------------------------------------
// Pool: 32 nodes/wave, same-graph fast path (batch sorted)
// ---------------------------------------------------------------------------

__global__ __launch_bounds__(256) void pool_kernel(const unsigned short* __restrict__ h16,
                                                   const int* __restrict__ batch,
                                                   float* __restrict__ gsum,
                                                   float* __restrict__ gcount) {
    int w = blockIdx.x * 4 + (threadIdx.x >> 6);
    int f = threadIdx.x & 63;
    int n0 = w * 32;
    if (n0 >= N_NODES) return;
    int n1 = min(n0 + 32, N_NODES);
    int g0 = batch[n0];
    int gend = batch[n1 - 1];
    if (g0 == gend) {
        float a0 = 0.f, a1 = 0.f, a2 = 0.f, a3 = 0.f;
        int n = n0;
        for (; n + 3 < n1; n += 4) {
            a0 += bfu(h16[(size_t)n * H + f]);
            a1 += bfu(h16[(size_t)(n + 1) * H + f]);
            a2 += bfu(h16[(size_t)(n + 2) * H + f]);
            a3 += bfu(h16[(size_t)(n + 3) * H + f]);
        }
        for (; n < n1; ++n) a0 += bfu(h16[(size_t)n * H + f]);
        atomicAdd(&gsum[g0 * H + f], (a0 + a1) + (a2 + a3));
        if (f == 0) atomicAdd(&gcount[g0], (float)(n1 - n0));
    } else {
        int curg = g0;
        float acc = 0.f;
        int cnt = 0;
        for (int n = n0; n < n1; ++n) {
            int g = batch[n];
            if (g != curg) {
                atomicAdd(&gsum[curg * H + f], acc);
                if (f == 0) atomicAdd(&gcount[curg], (float)cnt);
                acc = 0.f; cnt = 0; curg = g;
            }
            acc += bfu(h16[(size_t)n * H + f]);
            ++cnt;
        }
        atomicAdd(&gsum[curg * H + f], acc);
        if (f == 0) atomicAdd(&gcount[curg], (float)cnt);
    }
}

// ---------------------------------------------------------------------------
// Heads: policy handles 8 graphs per block
// ---------------------------------------------------------------------------

__global__ __launch_bounds__(256) void policy_kernel(const float* __restrict__ gsum,
                                                     const float* __restrict__ gcount,
                                                     const float* __restrict__ Wp,
                                                     const float* __restrict__ bp,
                                                     float* __restrict__ out) {
    __shared__ float gr[8][H];
    int g0 = blockIdx.y * 8;
    int t = threadIdx.x;
    #pragma unroll
    for (int r = 0; r < 2; ++r) {
        int idx = r * 256 + t;
        int gg = idx >> 6, f = idx & 63;
        float inv = 1.0f / fmaxf(gcount[g0 + gg], 1.0f);
        gr[gg][f] = gsum[(g0 + gg) * H + f] * inv;
    }
    __syncthreads();
    int a = blockIdx.x * 256 + t;
    if (a >= A_SZ) return;
    const float4* wp4 = (const float4*)(Wp + a * H);
    float bpa = bp[a];
    float acc[8];
    #pragma unroll
    for (int gg = 0; gg < 8; ++gg) acc[gg] = bpa;
    #pragma unroll
    for (int c = 0; c < 16; ++c) {
        float4 wv = wp4[c];
        #pragma unroll
        for (int gg = 0; gg < 8; ++gg) {
            acc[gg] += gr[gg][4 * c + 0] * wv.x + gr[gg][4 * c + 1] * wv.y
                     + gr[gg][4 * c + 2] * wv.z + gr[gg][4 * c + 3] * wv.w;
        }
    }
    #pragma unroll
    for (int gg = 0; gg < 8; ++gg)
        out[(g0 + gg) * A_SZ + a] = acc[gg];
}

__global__ void value_kernel(const float* __restrict__ gsum, const float* __restrict__ gcount,
                             const float* __restrict__ Wv, const float* __restrict__ bv,
                             float* __restrict__ out) {
    int g = threadIdx.x;
    if (g >= G_SZ) return;
    float inv = 1.0f / fmaxf(gcount[g], 1.0f);
    float acc = bv[0];
    #pragma unroll
    for (int k = 0; k < H; ++k) acc += gsum[g * H + k] * inv * Wv[k];
    out[G_SZ * A_SZ + g] = tanhf(acc);
}

// ---------------------------------------------------------------------------

extern "C" void kernel_launch(void* const* d_in, const int* in_sizes, int n_in,
                              void* d_out, int out_size, void* d_ws, size_t ws_size,
                              hipStream_t stream) {
    const float* x     = (const float*)d_in[0];
    const int*   ei    = (const int*)d_in[1];
    const int*   batch = (const int*)d_in[2];
    const float* W_enc = (const float*)d_in[3];
    const float* b_enc = (const float*)d_in[4];
    const float* Wl    = (const float*)d_in[5];
    const float* bl    = (const float*)d_in[6];
    const float* Wr    = (const float*)d_in[7];
    const float* Wp    = (const float*)d_in[8];
    const float* bp    = (const float*)d_in[9];
    const float* Wv    = (const float*)d_in[10];
    const float* bv    = (const float*)d_in[11];
    float* out = (float*)d_out;

    char* ws = (char*)d_ws;
    size_t off = 0;
    auto alloc = [&](size_t bytes) {
        char* p = ws + off;
        off = (off + bytes + 255) & ~(size_t)255;
        return p;
    };
    unsigned short* h16   = (unsigned short*)alloc((size_t)N_NODES * H * 2);
    unsigned char*  h8    = (unsigned char*)alloc((size_t)N_NODES * H);
    unsigned int*   agg16 = (unsigned int*)alloc((size_t)N_NODES * H * 2);
    int* row_start        = (int*)alloc((size_t)(N_NODES + 1) * 4);
    float* inv_deg        = (float*)alloc((size_t)N_NODES * 4);
    int* src_sorted       = (int*)alloc((size_t)N_EDGES * 4);
    unsigned int* pairs   = (unsigned int*)alloc((size_t)N_EDGES * 4);
    int* bhist            = (int*)alloc((NBUCK + 8) * 4);
    int* bucket_base      = (int*)alloc((NBUCK + 8) * 4);
    int* bcursor          = (int*)alloc((NBUCK + 8) * 4);
    unsigned short* wl16  = (unsigned short*)alloc((size_t)L_LAYERS * H * H * 2);
    unsigned short* wr16  = (unsigned short*)alloc((size_t)L_LAYERS * H * H * 2);
    float* gsum           = (float*)alloc((size_t)(G_SZ * H + G_SZ) * 4);
    float* gcount         = gsum + G_SZ * H;

    // CSR build (bucketed)
    hipMemsetAsync(bhist, 0, NBUCK * 4, stream);
    bucket_hist_kernel<<<NEBLK, 256, 0, stream>>>(ei, bhist);
    bucket_scan_kernel<<<1, 512, 0, stream>>>(bhist, bucket_base, bcursor);
    bucket_scatter_kernel<<<NEBLK, 256, 0, stream>>>(ei, bcursor, pairs);
    bucket_rank_kernel<<<NBUCK, 256, 0, stream>>>(pairs, bucket_base, row_start,
                                                  inv_deg, src_sorted);

    wconv_kernel<<<(L_LAYERS * H * H) / 256, 256, 0, stream>>>(Wl, Wr, wl16, wr16);
    encoder_kernel<<<N_NODES / 4, 256, 0, stream>>>(x, W_enc, b_enc, h16, h8);

    const int UPD_BLOCKS = N_NODES / 16;  // 6250, exact
    for (int l = 0; l < L_LAYERS; ++l) {
        aggregate_kernel<<<N_NODES / 16, 256, 0, stream>>>(h8, row_start, src_sorted,
                                                           inv_deg, agg16);
        update_kernel<<<UPD_BLOCKS, 256, 0, stream>>>(wl16 + (size_t)l * H * H, bl + l * H,
                                                      wr16 + (size_t)l * H * H,
                                                      (const unsigned short*)agg16, h16, h8);
    }

    hipMemsetAsync(gsum, 0, (size_t)(G_SZ * H + G_SZ) * 4, stream);
    const int POOL_BLOCKS = (N_NODES / 32 + 3) / 4 + 1;
    pool_kernel<<<POOL_BLOCKS, 256, 0, stream>>>(h16, batch, gsum, gcount);
    policy_kernel<<<dim3((A_SZ + 255) / 256, 8), 256, 0, stream>>>(gsum, gcount, Wp, bp, out);
    value_kernel<<<1, 64, 0, stream>>>(gsum, gcount, Wv, bv, out);
}